// Round 1
// baseline (1916.927 us; speedup 1.0000x reference)
//
#include <hip/hip_runtime.h>
#include <math.h>

#define D_DIM 256
#define K_CB  1024
#define EPS   1e-8f

// ws layout: scales[0..K_CB) = 1/max(||codebook_k||, eps)
//            scales[K_CB..K_CB+N) = 1/(max(||latent_n||, eps) * temperature)
__global__ __launch_bounds__(256) void qnorms_kernel(
    const float* __restrict__ latent,
    const float* __restrict__ codebook,
    const float* __restrict__ temp,
    float* __restrict__ scales,
    int N)
{
    const int w = blockIdx.x * 4 + (threadIdx.x >> 6);   // one wave per row
    const int lane = threadIdx.x & 63;
    if (w >= N + K_CB) return;
    const float* src = (w < K_CB) ? (codebook + (size_t)w * D_DIM)
                                  : (latent + (size_t)(w - K_CB) * D_DIM);
    float4 v = reinterpret_cast<const float4*>(src)[lane];   // 64 lanes x 4 = 256
    float ss = v.x * v.x + v.y * v.y + v.z * v.z + v.w * v.w;
#pragma unroll
    for (int off = 32; off > 0; off >>= 1) ss += __shfl_down(ss, off, 64);
    if (lane == 0) {
        const float inv = 1.0f / fmaxf(sqrtf(ss), EPS);
        scales[w] = (w < K_CB) ? inv : inv / temp[0];
    }
}

// Block: 256 threads, 64 latent rows. A tile resident in LDS (d-major).
// K processed in 4 tiles of 256 cols; D in chunks of 8 staged to LDS.
// Thread tile 8 rows x 8 cols; cols interleaved (64p + 2*tc + q) so LDS B
// reads are conflict-free. Fused gumbel + argmax epilogue per K-tile.
__global__ __launch_bounds__(256, 2) void qmain_kernel(
    const float* __restrict__ latent,
    const float* __restrict__ noise,
    const float* __restrict__ codebook,
    const float* __restrict__ scales,
    float* __restrict__ out,
    int N)
{
    __shared__ __align__(16) float As[D_DIM][64];   // [d][row]  64 KB
    __shared__ __align__(16) float Bs[8][256];      // [dd][col]  8 KB
    __shared__ float scale_s[64];
    __shared__ int   idx_s[64];

    const int tid  = threadIdx.x;
    const int row0 = blockIdx.x * 64;
    const int tr   = tid >> 5;    // 0..7  -> rows tr*8..tr*8+7
    const int tc   = tid & 31;    // 0..31 -> cols 64p + 2*tc + q

    // ---- Load A (64 rows x 256) transposed into LDS (coalesced 1KB/row reads) ----
    {
        const int f4   = tid & 63;
        const int rsub = tid >> 6;
#pragma unroll
        for (int p = 0; p < 16; ++p) {
            const int row = p * 4 + rsub;
            float4 v = reinterpret_cast<const float4*>(
                latent + (size_t)(row0 + row) * D_DIM)[f4];
            As[f4 * 4 + 0][row] = v.x;
            As[f4 * 4 + 1][row] = v.y;
            As[f4 * 4 + 2][row] = v.z;
            As[f4 * 4 + 3][row] = v.w;
        }
    }
    if (tid < 64) scale_s[tid] = scales[K_CB + row0 + tid];
    __syncthreads();

    float rscale[8];
#pragma unroll
    for (int i = 0; i < 8; ++i) rscale[i] = scale_s[tr * 8 + i];

    float rmax[8];
    int   ridx[8];
#pragma unroll
    for (int i = 0; i < 8; ++i) { rmax[i] = -INFINITY; ridx[i] = 0x7fffffff; }

    for (int kt = 0; kt < 4; ++kt) {
        const int c0 = kt * 256;
        float acc[8][8];
#pragma unroll
        for (int i = 0; i < 8; ++i)
#pragma unroll
            for (int j = 0; j < 8; ++j) acc[i][j] = 0.0f;

        for (int dc = 0; dc < 32; ++dc) {
            __syncthreads();   // previous chunk's readers done
            {
                // stage codebook[c0..c0+255][dc*8..dc*8+7] -> Bs[dd][col]
                const int cc = tid >> 1;
                const int f4 = tid & 1;
#pragma unroll
                for (int p = 0; p < 2; ++p) {
                    const int c = p * 128 + cc;
                    float4 v = reinterpret_cast<const float4*>(
                        codebook + (size_t)(c0 + c) * D_DIM + dc * 8)[f4];
                    Bs[f4 * 4 + 0][c] = v.x;
                    Bs[f4 * 4 + 1][c] = v.y;
                    Bs[f4 * 4 + 2][c] = v.z;
                    Bs[f4 * 4 + 3][c] = v.w;
                }
            }
            __syncthreads();
#pragma unroll
            for (int dd = 0; dd < 8; ++dd) {
                const int d = dc * 8 + dd;
                const float4 a0 = *reinterpret_cast<const float4*>(&As[d][tr * 8]);
                const float4 a1 = *reinterpret_cast<const float4*>(&As[d][tr * 8 + 4]);
                const float a[8] = {a0.x, a0.y, a0.z, a0.w, a1.x, a1.y, a1.z, a1.w};
                float b[8];
#pragma unroll
                for (int p = 0; p < 4; ++p) {
                    const float2 bv =
                        *reinterpret_cast<const float2*>(&Bs[dd][p * 64 + tc * 2]);
                    b[p * 2 + 0] = bv.x;
                    b[p * 2 + 1] = bv.y;
                }
#pragma unroll
                for (int i = 0; i < 8; ++i)
#pragma unroll
                    for (int j = 0; j < 8; ++j)
                        acc[i][j] = fmaf(a[i], b[j], acc[i][j]);
            }
        }

        // ---- epilogue for this 256-col tile: gumbel + running argmax ----
        float cscale[8];
#pragma unroll
        for (int p = 0; p < 4; ++p) {
            cscale[p * 2 + 0] = scales[c0 + p * 64 + tc * 2 + 0];
            cscale[p * 2 + 1] = scales[c0 + p * 64 + tc * 2 + 1];
        }
#pragma unroll
        for (int i = 0; i < 8; ++i) {
            const int grow = row0 + tr * 8 + i;
            const float* nrow = noise + (size_t)grow * K_CB + c0;
            float v = -INFINITY;
            int   vi = 0x7fffffff;
#pragma unroll
            for (int p = 0; p < 4; ++p) {
                const float2 u2 =
                    *reinterpret_cast<const float2*>(&nrow[p * 64 + tc * 2]);
                const float uu[2] = {u2.x, u2.y};
#pragma unroll
                for (int q = 0; q < 2; ++q) {
                    const float g = -logf(-logf(uu[q]));
                    const float l = fmaf(acc[i][p * 2 + q] * rscale[i],
                                         cscale[p * 2 + q], g);
                    const int cidx = c0 + p * 64 + tc * 2 + q;
                    if (l > v || (l == v && cidx < vi)) { v = l; vi = cidx; }
                }
            }
            // reduce across the 32 lanes (tc) sharing this row
#pragma unroll
            for (int off = 16; off > 0; off >>= 1) {
                const float ov = __shfl_xor(v, off, 64);
                const int   oi = __shfl_xor(vi, off, 64);
                if (ov > v || (ov == v && oi < vi)) { v = ov; vi = oi; }
            }
            if (v > rmax[i] || (v == rmax[i] && vi < ridx[i])) {
                rmax[i] = v;
                ridx[i] = vi;
            }
        }
    }

    if (tc == 0) {
#pragma unroll
        for (int i = 0; i < 8; ++i) idx_s[tr * 8 + i] = ridx[i];
    }
    __syncthreads();

    // ---- gather: out[row] = codebook[idx[row]] (coalesced 1KB per row) ----
    {
        const int lane = tid & 63;
        const int rr   = tid >> 6;
#pragma unroll
        for (int p = 0; p < 16; ++p) {
            const int row = rr * 16 + p;
            const int idx = idx_s[row];
            const float4 v =
                reinterpret_cast<const float4*>(codebook + (size_t)idx * D_DIM)[lane];
            reinterpret_cast<float4*>(out + (size_t)(row0 + row) * D_DIM)[lane] = v;
        }
    }
}

extern "C" void kernel_launch(void* const* d_in, const int* in_sizes, int n_in,
                              void* d_out, int out_size, void* d_ws, size_t ws_size,
                              hipStream_t stream)
{
    const float* latent   = (const float*)d_in[0];
    const float* noise    = (const float*)d_in[1];
    const float* codebook = (const float*)d_in[2];
    const float* temp     = (const float*)d_in[3];
    float* out    = (float*)d_out;
    float* scales = (float*)d_ws;                // (K_CB + N) floats
    const int N = in_sizes[0] / D_DIM;           // 131072

    const int nw = (N + K_CB + 3) / 4;           // 4 waves per block
    qnorms_kernel<<<nw, 256, 0, stream>>>(latent, codebook, temp, scales, N);
    qmain_kernel<<<N / 64, 256, 0, stream>>>(latent, noise, codebook, scales, out, N);
}